// Round 7
// baseline (113.535 us; speedup 1.0000x reference)
//
#include <hip/hip_runtime.h>
#include <math.h>

#define NF 2048
#define ROWS (32 * 1024)
#define CELLS (NF / 4)   // 512 float4 cells per row
#define PHASES 8         // phase t = cells [t*64, t*64+64)
#define NBLOCKS 2048     // 2048 blocks x 8 waves x 2 rows = 32768 rows
#define BLKTHREADS 512

typedef float f32x4 __attribute__((ext_vector_type(4)));

// ---- DPP cross-lane helpers (pure VALU, no DS-pipe traffic) ----------------
// wave_shr:1 (0x138): dest[n] = src[n-1]  (lane 0 <- oldv)
// wave_shl:1 (0x130): dest[n] = src[n+1]  (lane 63 <- oldv)
__device__ __forceinline__ float dpp_up1(float v, float oldv) {
  return __int_as_float(__builtin_amdgcn_update_dpp(
      __float_as_int(oldv), __float_as_int(v), 0x138, 0xF, 0xF, false));
}
__device__ __forceinline__ float dpp_dn1(float v, float oldv) {
  return __int_as_float(__builtin_amdgcn_update_dpp(
      __float_as_int(oldv), __float_as_int(v), 0x130, 0xF, 0xF, false));
}
__device__ __forceinline__ float bcast_lane(float v, int lane) {
  return __int_as_float(__builtin_amdgcn_readlane(__float_as_int(v), lane));
}

// ---------------------------------------------------------------------------
// Kernel 1: factorize the tridiagonal matrix once (unchanged math).
// ---------------------------------------------------------------------------
__global__ __launch_bounds__(256) void precompute_kernel(
    const float* __restrict__ d, const float* __restrict__ l,
    const float* __restrict__ u, float* __restrict__ wsg,
    float* __restrict__ wsc, float* __restrict__ wsib) {
  __shared__ float diag_s[NF], tl_s[NF], tu_s[NF], b_s[NF];
  const int tid = threadIdx.x;

  for (int i = tid; i < NF; i += 256) {
    float dv = d[i];
    float sp = (dv > 20.f) ? dv : log1pf(expf(dv));  // softplus, safe
    diag_s[i] = sp + 2.f;
    tl_s[i] = (i < NF - 1) ? tanhf(l[i]) : 0.f;
    tu_s[i] = (i < NF - 1) ? tanhf(u[i]) : 0.f;
  }
  __syncthreads();

  if (tid < 64) {
    const int lane = tid;
    float T00 = 1.f, T01 = 0.f, T10 = 0.f, T11 = 1.f;
#pragma unroll 1
    for (int j = 0; j < 32; ++j) {
      int i = lane * 32 + j;
      float a = diag_s[i];
      float b = (i > 0) ? -tl_s[i - 1] * tu_s[i - 1] : 0.f;
      float n00 = a * T00 + b * T10;
      float n01 = a * T01 + b * T11;
      T10 = T00; T11 = T01; T00 = n00; T01 = n01;
      float s = 1.f / (fabsf(T00) + fabsf(T01) + 1e-30f);
      T00 *= s; T01 *= s; T10 *= s; T11 *= s;
    }
    for (int ofs = 1; ofs < 64; ofs <<= 1) {
      float U00 = __shfl_up(T00, ofs, 64);
      float U01 = __shfl_up(T01, ofs, 64);
      float U10 = __shfl_up(T10, ofs, 64);
      float U11 = __shfl_up(T11, ofs, 64);
      if (lane >= ofs) {
        float n00 = T00 * U00 + T01 * U10;
        float n01 = T00 * U01 + T01 * U11;
        float n10 = T10 * U00 + T11 * U10;
        float n11 = T10 * U01 + T11 * U11;
        T00 = n00; T01 = n01; T10 = n10; T11 = n11;
        float s = 1.f / (fabsf(T00) + fabsf(T01) + 1e-30f);
        T00 *= s; T01 *= s; T10 *= s; T11 *= s;
      }
    }
    float p1 = __shfl_up(T00, 1, 64);
    float p2 = __shfl_up(T10, 1, 64);
    float bp = (lane == 0) ? 1.f : p1 / p2;  // b'_{lane*32-1}
#pragma unroll 1
    for (int j = 0; j < 32; ++j) {
      int i = lane * 32 + j;
      float km1 = (i > 0) ? tl_s[i - 1] * tu_s[i - 1] : 0.f;
      float bv = diag_s[i] - km1 / bp;
      b_s[i] = bv;
      bp = bv;
    }
  }
  __syncthreads();

  for (int i = tid; i < NF; i += 256) {
    float invb = 1.f / b_s[i];
    wsg[i] = (i > 0) ? -tl_s[i - 1] / b_s[i - 1] : 0.f;
    wsc[i] = (i < NF - 1) ? -tu_s[i] * invb : 0.f;
    wsib[i] = invb;
  }
}

// ---------------------------------------------------------------------------
// Kernel 2: batched solve. 8-wave blocks (LDS shared by 8 waves -> 32
// waves/CU occupancy cap instead of 24); x-loads issued BEFORE LDS staging
// so the HBM stream starts at block launch and staging hides under it.
// One row-pair per wave; cross-lane via DPP/readlane only.
// Truncation (|g|,|c| <= ~0.2 guaranteed by diagonal dominance): single scan
// step (span-8 products < 2.3e-6); carry fold with exact 2-cell factor A2;
// inter-phase homogeneous factor over 256 elems underflows -> carries are
// plain readlane broadcasts. All errors ~1e-5 << 4.06e-2 threshold.
// ---------------------------------------------------------------------------
__global__ __launch_bounds__(BLKTHREADS) void solve_kernel(
    const float* __restrict__ x, const float* __restrict__ wsg,
    const float* __restrict__ wsc, const float* __restrict__ wsib,
    float* __restrict__ y) {
  __shared__ float4 g_s[CELLS], c_s[CELLS], ib_s[CELLS];

  const int lane = threadIdx.x & 63;
  const unsigned wave = (blockIdx.x * BLKTHREADS + threadIdx.x) >> 6;
  const unsigned o0 = (2u * wave) * (NF / 4) + lane;  // cell index, 32-bit
  const unsigned o1 = o0 + (NF / 4);
  const float4* xb = (const float4*)x;
  float4* yb = (float4*)y;

  // issue the block's HBM stream first
  float4 v0[PHASES], v1[PHASES];
#pragma unroll
  for (int t = 0; t < PHASES; ++t) {
    v0[t] = xb[o0 + t * 64];
    v1[t] = xb[o1 + t * 64];
  }

  // stage coefficients (L2-hot; overlaps the x-load latency)
  for (int t = threadIdx.x; t < CELLS; t += BLKTHREADS) {
    g_s[t] = ((const float4*)wsg)[t];
    c_s[t] = ((const float4*)wsc)[t];
    ib_s[t] = ((const float4*)wsib)[t];
  }
  __syncthreads();

  const float4* gs = &g_s[lane];
  const float4* cs = &c_s[lane];
  const float4* ibs = &ib_s[lane];

  // ---------------- forward: d_i = x_i + g_i*d_{i-1} ----------------
  {
    float ct0 = 0.f, ct1 = 0.f;  // incoming carry (wave-uniform)
#pragma unroll
    for (int t = 0; t < PHASES; ++t) {
      float4 g = gs[t * 64];
      float4 d0 = v0[t], d1 = v1[t];
      // local pass within the 4-elem cell
      d0.y = fmaf(g.y, d0.x, d0.y);
      d0.z = fmaf(g.z, d0.y, d0.z);
      d0.w = fmaf(g.w, d0.z, d0.w);
      d1.y = fmaf(g.y, d1.x, d1.y);
      d1.z = fmaf(g.z, d1.y, d1.z);
      d1.w = fmaf(g.w, d1.z, d1.w);
      float A = g.x * g.y * g.z * g.w;   // per-cell factor (shared by rows)
      float A2 = A * dpp_up1(A, 1.f);    // 2-cell factor for carry fold
      // single scan step (span 8) + carry fold
      float B0 = fmaf(A, dpp_up1(d0.w, 0.f), d0.w);
      float B1 = fmaf(A, dpp_up1(d1.w, 0.f), d1.w);
      B0 = fmaf(A2, ct0, B0);
      B1 = fmaf(A2, ct1, B1);
      // per-cell incoming value (lane 0 inherits carry via DPP old operand)
      float vin0 = dpp_up1(B0, ct0);
      float vin1 = dpp_up1(B1, ct1);
      ct0 = bcast_lane(B0, 63);
      ct1 = bcast_lane(B1, 63);
      // apply
      float p = g.x;
      d0.x = fmaf(p, vin0, d0.x);
      d1.x = fmaf(p, vin1, d1.x);
      p *= g.y;
      d0.y = fmaf(p, vin0, d0.y);
      d1.y = fmaf(p, vin1, d1.y);
      p *= g.z;
      d0.z = fmaf(p, vin0, d0.z);
      d1.z = fmaf(p, vin1, d1.z);
      p *= g.w;
      d0.w = fmaf(p, vin0, d0.w);
      d1.w = fmaf(p, vin1, d1.w);
      v0[t] = d0;
      v1[t] = d1;
    }
  }

  // ---------------- backward: y_i = ib_i*d_i + c_i*y_{i+1} ----------------
  {
    float ct0 = 0.f, ct1 = 0.f;
#pragma unroll
    for (int t = PHASES - 1; t >= 0; --t) {
      float4 c = cs[t * 64];
      float4 ib = ibs[t * 64];
      float4 d0 = v0[t], d1 = v1[t];
      float4 w0, w1;
      // local suffix pass within cell
      w0.w = ib.w * d0.w;
      w0.z = fmaf(c.z, w0.w, ib.z * d0.z);
      w0.y = fmaf(c.y, w0.z, ib.y * d0.y);
      w0.x = fmaf(c.x, w0.y, ib.x * d0.x);
      w1.w = ib.w * d1.w;
      w1.z = fmaf(c.z, w1.w, ib.z * d1.z);
      w1.y = fmaf(c.y, w1.z, ib.y * d1.y);
      w1.x = fmaf(c.x, w1.y, ib.x * d1.x);
      float A = c.x * c.y * c.z * c.w;
      float A2 = A * dpp_dn1(A, 1.f);
      float B0 = fmaf(A, dpp_dn1(w0.x, 0.f), w0.x);
      float B1 = fmaf(A, dpp_dn1(w1.x, 0.f), w1.x);
      B0 = fmaf(A2, ct0, B0);
      B1 = fmaf(A2, ct1, B1);
      float vin0 = dpp_dn1(B0, ct0);  // lane 63 inherits carry
      float vin1 = dpp_dn1(B1, ct1);
      ct0 = bcast_lane(B0, 0);
      ct1 = bcast_lane(B1, 0);
      // apply
      float p = c.w;
      w0.w = fmaf(p, vin0, w0.w);
      w1.w = fmaf(p, vin1, w1.w);
      p *= c.z;
      w0.z = fmaf(p, vin0, w0.z);
      w1.z = fmaf(p, vin1, w1.z);
      p *= c.y;
      w0.y = fmaf(p, vin0, w0.y);
      w1.y = fmaf(p, vin1, w1.y);
      p *= c.x;
      w0.x = fmaf(p, vin0, w0.x);
      w1.x = fmaf(p, vin1, w1.x);
      // nontemporal stores: y is never re-read; don't evict x from L2/L3
      __builtin_nontemporal_store(*(const f32x4*)&w0, (f32x4*)&yb[o0 + t * 64]);
      __builtin_nontemporal_store(*(const f32x4*)&w1, (f32x4*)&yb[o1 + t * 64]);
    }
  }
}

extern "C" void kernel_launch(void* const* d_in, const int* in_sizes, int n_in,
                              void* d_out, int out_size, void* d_ws,
                              size_t ws_size, hipStream_t stream) {
  const float* x = (const float*)d_in[0];
  const float* d = (const float*)d_in[1];
  const float* l = (const float*)d_in[2];
  const float* u = (const float*)d_in[3];
  float* out = (float*)d_out;

  float* wsg = (float*)d_ws;   // 2048 floats, plain order
  float* wsc = wsg + NF;       // 2048 floats
  float* wsib = wsc + NF;      // 2048 floats

  precompute_kernel<<<1, 256, 0, stream>>>(d, l, u, wsg, wsc, wsib);
  // grid MUST be exactly NBLOCKS x BLKTHREADS: 16384 waves x 2 adjacent rows.
  solve_kernel<<<NBLOCKS, BLKTHREADS, 0, stream>>>(x, wsg, wsc, wsib, out);
}